// Round 11
// baseline (89.166 us; speedup 1.0000x reference)
//
#include <hip/hip_runtime.h>
#include <hip/hip_bf16.h>

#define B_ 4
#define N_ 2048
#define C_ 256
#define H_ 8
#define D_ 32

typedef __attribute__((ext_vector_type(4))) short bf16x4;
typedef __attribute__((ext_vector_type(8))) short bf16x8;
typedef __attribute__((ext_vector_type(16))) float f32x16;

static __device__ __forceinline__ float b2f(short u) {
    unsigned v = ((unsigned)(unsigned short)u) << 16;
    return __builtin_bit_cast(float, v);
}
static __device__ __forceinline__ short f2bs(float f) {
    __hip_bfloat16 h = __float2bfloat16(f);
    return __builtin_bit_cast(short, h);
}

// Fragment k-map (32x32x16 bf16): slot s (0..15), lane-half hi:
//   dd = hi*4 + (s&3) + 8*(s>>2); inverse hi=(dd>>2)&1, s=(dd&3)+4*(dd>>3)
// REGISTER BUDGET (hard-won): attn body = exactly 128 unified regs/thread
// (the 4-waves/EU budget). EVERY modification spilled or regressed:
//   R5 (256,8) cap, R6 (256,6) cap, R7 +pipeline stage, R8 split-m blocks,
//   R9 setprio+XCD-swizzle (sched pressure -> 24MB scratch),
//   R10 u8 mask byte-extracts (+VALU, +temps -> 53MB scratch).
// This file = R4-exact attn body + merged prep + dual-acc GEMMs. Do not
// touch the attn body without checking WRITE_SIZE for scratch.

// ---------------------------------------------------------------------------
// Merged prep: x relayout (blocks 0..2047), W relayout (2048..2303),
// mask relayout -> premultiplied bf16 C-fragment order (2304..2815).
// ---------------------------------------------------------------------------
__global__ __launch_bounds__(256) void prep_relayout(const float* __restrict__ x,
                                                     const float* __restrict__ Wq,
                                                     const float* __restrict__ Wo,
                                                     const float* __restrict__ mask,
                                                     short* __restrict__ xF,
                                                     short* __restrict__ wqF,
                                                     short* __restrict__ woF,
                                                     short* __restrict__ maskF) {
    const int t = threadIdx.x;
    const int b = blockIdx.x;
    if (b < 2048) {
        const int idx = b * 256 + t;
        const int row = idx >> 6, c0 = (idx & 63) * 4;
        const float4 f4 = *(const float4*)(x + (size_t)row * 256 + c0);
        const int mt = row >> 5, l5 = row & 31;
        const int kt = c0 >> 5, dd0 = c0 & 31;
        const int hi = (dd0 >> 2) & 1, s0 = 4 * (dd0 >> 3);
        bf16x4 o;
        o[0] = f2bs(f4.x); o[1] = f2bs(f4.y); o[2] = f2bs(f4.z); o[3] = f2bs(f4.w);
        *(bf16x4*)(xF + (((size_t)mt * 8 + kt) * 32 + l5) * 32 + hi * 16 + s0) = o;
    } else if (b < 2304) {
        int idx = (b - 2048) * 256 + t;
        const float* W; short* dst; int ncols;
        if (idx < 49152) { W = Wq; dst = wqF; ncols = 768; }
        else { idx -= 49152; W = Wo; dst = woF; ncols = 256; }
        const int f4pr = ncols >> 2;
        const int row = idx / f4pr, c0 = (idx % f4pr) * 4;
        const float4 f4 = *(const float4*)(W + (size_t)row * ncols + c0);
        const int kt = row >> 5, dd = row & 31;
        const int hi = (dd >> 2) & 1, s = (dd & 3) + 4 * (dd >> 3);
        const float vals[4] = {f4.x, f4.y, f4.z, f4.w};
#pragma unroll
        for (int j = 0; j < 4; ++j) {
            const int col = c0 + j, nt = col >> 5, l5 = col & 31;
            dst[(((size_t)nt * 8 + kt) * 32 + l5) * 32 + hi * 16 + s] = f2bs(vals[j]);
        }
    } else {
        const int bid = b - 2304;           // 0..511
        const int bx = bid & 15, by = bid >> 4;
        const int n = by * 64 + (t & 63);
        const int mt = bx * 4 + (t >> 6);
        const float cf = 0.17677669529663687f * 1.4426950408889634f;
        float v[32];
        const float4* src = (const float4*)(mask + (size_t)n * N_ + mt * 32);
#pragma unroll
        for (int i = 0; i < 8; ++i) {
            const float4 f4 = src[i];
            v[i * 4 + 0] = f4.x; v[i * 4 + 1] = f4.y;
            v[i * 4 + 2] = f4.z; v[i * 4 + 3] = f4.w;
        }
#pragma unroll
        for (int hi = 0; hi < 2; ++hi) {
            bf16x8 o0, o1;
#pragma unroll
            for (int r = 0; r < 16; ++r) {
                const int crow = (r & 3) + 8 * (r >> 2) + 4 * hi;
                const short s = f2bs(cf * (0.1f + 0.9f * v[crow]));
                if (r < 8) o0[r] = s; else o1[r - 8] = s;
            }
            short* dst = maskF + ((size_t)(mt * 2 + hi) * N_ + n) * 16;
            *(bf16x8*)dst = o0;
            *(bf16x8*)(dst + 8) = o1;
        }
    }
}

// ---------------------------------------------------------------------------
// QKV projection, MFMA (dual accumulator for MFMA ILP).
// ---------------------------------------------------------------------------
__global__ __launch_bounds__(256, 4) void qkv_mfma(const short* __restrict__ xF,
                                                   const short* __restrict__ wqF,
                                                   const float* __restrict__ bias,
                                                   short* __restrict__ qb,
                                                   short* __restrict__ kbF,
                                                   short* __restrict__ vbF) {
    __shared__ short sc[4][32 * 34];
    const int t = threadIdx.x;
    const int w = t >> 6, lane = t & 63, l5 = lane & 31, hi = lane >> 5;
    const int tile = blockIdx.x * 4 + w;
    const int nt = tile % 24, mt = tile / 24;
    f32x16 acc0, acc1;
#pragma unroll
    for (int i = 0; i < 16; ++i) { acc0[i] = 0.f; acc1[i] = 0.f; }
    const short* ap = xF + ((size_t)mt * 8 * 32) * 32 + l5 * 32 + hi * 16;
    const short* bp = wqF + ((size_t)nt * 8 * 32) * 32 + l5 * 32 + hi * 16;
#pragma unroll
    for (int kt = 0; kt < 8; kt += 2) {
        const bf16x8 a0 = *(const bf16x8*)(ap + kt * 1024);
        const bf16x8 a1 = *(const bf16x8*)(ap + kt * 1024 + 8);
        const bf16x8 b0 = *(const bf16x8*)(bp + kt * 1024);
        const bf16x8 b1 = *(const bf16x8*)(bp + kt * 1024 + 8);
        const bf16x8 a2 = *(const bf16x8*)(ap + kt * 1024 + 1024);
        const bf16x8 a3 = *(const bf16x8*)(ap + kt * 1024 + 1032);
        const bf16x8 b2 = *(const bf16x8*)(bp + kt * 1024 + 1024);
        const bf16x8 b3 = *(const bf16x8*)(bp + kt * 1024 + 1032);
        acc0 = __builtin_amdgcn_mfma_f32_32x32x16_bf16(a0, b0, acc0, 0, 0, 0);
        acc1 = __builtin_amdgcn_mfma_f32_32x32x16_bf16(a2, b2, acc1, 0, 0, 0);
        acc0 = __builtin_amdgcn_mfma_f32_32x32x16_bf16(a1, b1, acc0, 0, 0, 0);
        acc1 = __builtin_amdgcn_mfma_f32_32x32x16_bf16(a3, b3, acc1, 0, 0, 0);
    }
    const float bq = bias[nt * 32 + l5];
    short* myc = sc[w];
#pragma unroll
    for (int r = 0; r < 16; ++r)
        myc[((r & 3) + 8 * (r >> 2) + 4 * hi) * 34 + l5] =
            f2bs(acc0[r] + acc1[r] + bq);
    __syncthreads();

    const int h = nt & 7, t3 = nt >> 3;
    const int mtk = mt & 63;
    const size_t bh = (size_t)(mt >> 6) * 8 + h;
    if (t3 == 0) {
        const bf16x8 r0 = *(const bf16x8*)(myc + l5 * 34 + hi * 16);
        const bf16x8 r1 = *(const bf16x8*)(myc + l5 * 34 + hi * 16 + 8);
        short* dst = qb + (bh * N_ + (size_t)mtk * 32 + l5) * D_ + hi * 16;
        *(bf16x8*)dst = r0;
        *(bf16x8*)(dst + 8) = r1;
    } else if (t3 == 1) {
        bf16x8 o0, o1;
#pragma unroll
        for (int s = 0; s < 16; ++s) {
            const int dd = hi * 4 + (s & 3) + 8 * (s >> 2);
            const short vv = myc[l5 * 34 + dd];
            if (s < 8) o0[s] = vv; else o1[s - 8] = vv;
        }
        short* dst = kbF + ((bh * 64 + mtk) * 32 + l5) * 32 + hi * 16;
        *(bf16x8*)dst = o0;
        *(bf16x8*)(dst + 8) = o1;
    } else {
        bf16x8 o0, o1;
#pragma unroll
        for (int s = 0; s < 16; ++s) {
            const int nl = hi * 4 + (s & 3) + 8 * (s >> 2);
            const short vv = myc[nl * 34 + l5];
            if (s < 8) o0[s] = vv; else o1[s - 8] = vv;
        }
        short* dst = vbF + ((bh * 64 + mtk) * 32 + l5) * 32 + hi * 16;
        *(bf16x8*)dst = o0;
        *(bf16x8*)(dst + 8) = o1;
    }
}

// ---------------------------------------------------------------------------
// MFMA flash attention — R4 body EXACTLY (proven 44.9us, no spill).
// Grid 1024 = (bh, qg64). Block = 4 waves (split-m x4 in-block), 64 q-rows
// (2-tile ILP). bf16 premultiplied mask fragments. Direct aoF fragment write.
// ---------------------------------------------------------------------------
__global__ __launch_bounds__(256, 4) void attn_mfma(const short* __restrict__ qb,
                                                    const short* __restrict__ kbF,
                                                    const short* __restrict__ vbF,
                                                    const short* __restrict__ maskF,
                                                    short* __restrict__ aoF) {
    __shared__ float red[4][32][33];
    __shared__ float Ls[4][32];
    const int t = threadIdx.x;
    const int w = t >> 6, lane = t & 63, l5 = lane & 31, hi = lane >> 5;
    const int hi4 = hi * 4;
    const int bh = blockIdx.x >> 5, qg = blockIdx.x & 31;
    const int q0 = qg * 64;
    const int nqA = q0 + l5, nqB = q0 + 32 + l5;

    const short* qrA = qb + ((size_t)bh * N_ + nqA) * D_;
    const short* qrB = qb + ((size_t)bh * N_ + nqB) * D_;
    const bf16x8 qfA0 = __builtin_shufflevector(*(const bf16x4*)(qrA + hi4),
                                                *(const bf16x4*)(qrA + hi4 + 8),
                                                0, 1, 2, 3, 4, 5, 6, 7);
    const bf16x8 qfA1 = __builtin_shufflevector(*(const bf16x4*)(qrA + hi4 + 16),
                                                *(const bf16x4*)(qrA + hi4 + 24),
                                                0, 1, 2, 3, 4, 5, 6, 7);
    const bf16x8 qfB0 = __builtin_shufflevector(*(const bf16x4*)(qrB + hi4),
                                                *(const bf16x4*)(qrB + hi4 + 8),
                                                0, 1, 2, 3, 4, 5, 6, 7);
    const bf16x8 qfB1 = __builtin_shufflevector(*(const bf16x4*)(qrB + hi4 + 16),
                                                *(const bf16x4*)(qrB + hi4 + 24),
                                                0, 1, 2, 3, 4, 5, 6, 7);
    f32x16 accA, accB;
#pragma unroll
    for (int i = 0; i < 16; ++i) { accA[i] = 0.f; accB[i] = 0.f; }
    float lsA0 = 0.f, lsA1 = 0.f, lsB0 = 0.f, lsB1 = 0.f;

    const size_t fragbase = (size_t)bh * 64 * 1024;
#pragma unroll 4
    for (int i = 0; i < 16; ++i) {
        const int mt = w * 16 + i;
        // mask loads first (independent of MFMA results -> hoistable)
        const short* mpA = maskF + ((size_t)(mt * 2 + hi) * N_ + nqA) * 16;
        const short* mpB = maskF + ((size_t)(mt * 2 + hi) * N_ + nqB) * 16;
        const bf16x8 mA0 = *(const bf16x8*)mpA;
        const bf16x8 mA1 = *(const bf16x8*)(mpA + 8);
        const bf16x8 mB0 = *(const bf16x8*)mpB;
        const bf16x8 mB1 = *(const bf16x8*)(mpB + 8);
        const short* vp = vbF + fragbase + (size_t)mt * 1024 + l5 * 32 + hi * 16;
        const bf16x8 vf0 = *(const bf16x8*)vp;
        const bf16x8 vf1 = *(const bf16x8*)(vp + 8);

        const short* kp = kbF + fragbase + (size_t)mt * 1024 + l5 * 32 + hi * 16;
        const bf16x8 af0 = *(const bf16x8*)kp;
        const bf16x8 af1 = *(const bf16x8*)(kp + 8);
        f32x16 sA, sB;
#pragma unroll
        for (int j = 0; j < 16; ++j) { sA[j] = 0.f; sB[j] = 0.f; }
        sA = __builtin_amdgcn_mfma_f32_32x32x16_bf16(af0, qfA0, sA, 0, 0, 0);
        sB = __builtin_amdgcn_mfma_f32_32x32x16_bf16(af0, qfB0, sB, 0, 0, 0);
        sA = __builtin_amdgcn_mfma_f32_32x32x16_bf16(af1, qfA1, sA, 0, 0, 0);
        sB = __builtin_amdgcn_mfma_f32_32x32x16_bf16(af1, qfB1, sB, 0, 0, 0);

        bf16x8 pfA0, pfA1, pfB0, pfB1;
#pragma unroll
        for (int r = 0; r < 16; ++r) {
            const float fmA = b2f(r < 8 ? mA0[r] : mA1[r - 8]);
            const float fmB = b2f(r < 8 ? mB0[r] : mB1[r - 8]);
            const float pA = __builtin_amdgcn_exp2f(sA[r] * fmA);
            const float pB = __builtin_amdgcn_exp2f(sB[r] * fmB);
            if (r < 8) { lsA0 += pA; lsB0 += pB; }
            else       { lsA1 += pA; lsB1 += pB; }
            const short hA = f2bs(pA), hB = f2bs(pB);
            if (r < 8) { pfA0[r] = hA; pfB0[r] = hB; }
            else       { pfA1[r - 8] = hA; pfB1[r - 8] = hB; }
        }
        accA = __builtin_amdgcn_mfma_f32_32x32x16_bf16(vf0, pfA0, accA, 0, 0, 0);
        accB = __builtin_amdgcn_mfma_f32_32x32x16_bf16(vf0, pfB0, accB, 0, 0, 0);
        accA = __builtin_amdgcn_mfma_f32_32x32x16_bf16(vf1, pfA1, accA, 0, 0, 0);
        accB = __builtin_amdgcn_mfma_f32_32x32x16_bf16(vf1, pfB1, accB, 0, 0, 0);
    }
    const float lsA = lsA0 + lsA1, lsB = lsB0 + lsB1;

    // two reduction rounds (one per q-tile), reusing the same LDS buffer
    const int h = bh & 7;
    const int gmtb = (bh >> 3) * 64 + qg * 2;
#pragma unroll
    for (int tq = 0; tq < 2; ++tq) {
        if (tq) __syncthreads();
        const float lsum = tq ? lsB : lsA;
        const f32x16 acc = tq ? accB : accA;
        const float lt = lsum + __shfl_xor(lsum, 32);
        Ls[w][l5] = lt;
#pragma unroll
        for (int r = 0; r < 16; ++r)
            red[w][(r & 3) + 8 * (r >> 2) + hi4][l5] = acc[r];
        __syncthreads();
        const int row = t & 31, hi2 = (t >> 5) & 1, sh = t >> 6;
        const float inv = 1.0f / (Ls[0][row] + Ls[1][row] + Ls[2][row] + Ls[3][row]);
        bf16x4 o;
#pragma unroll
        for (int j = 0; j < 4; ++j) {
            const int dd = hi2 * 4 + j + 8 * sh;
            o[j] = f2bs((red[0][dd][row] + red[1][dd][row] +
                         red[2][dd][row] + red[3][dd][row]) * inv);
        }
        const size_t gmt = gmtb + tq;
        *(bf16x4*)(aoF + ((gmt * 8 + h) * 32 + row) * 32 + hi2 * 16 + sh * 4) = o;
    }
}

// ---------------------------------------------------------------------------
// Output projection, MFMA (dual accumulator).
// ---------------------------------------------------------------------------
__global__ __launch_bounds__(256, 4) void out_mfma(const short* __restrict__ aoF,
                                                   const short* __restrict__ woF,
                                                   const float* __restrict__ bias,
                                                   float* __restrict__ out) {
    const int t = threadIdx.x;
    const int w = t >> 6, lane = t & 63, l5 = lane & 31, hi = lane >> 5;
    const int tile = blockIdx.x * 4 + w;
    const int nt = tile & 7, mt = tile >> 3;
    f32x16 acc0, acc1;
#pragma unroll
    for (int i = 0; i < 16; ++i) { acc0[i] = 0.f; acc1[i] = 0.f; }
    const short* ap = aoF + (size_t)mt * 8192 + l5 * 32 + hi * 16;
    const short* bp = woF + (size_t)nt * 8192 + l5 * 32 + hi * 16;
#pragma unroll
    for (int kt = 0; kt < 8; kt += 2) {
        const bf16x8 a0 = *(const bf16x8*)(ap + kt * 1024);
        const bf16x8 a1 = *(const bf16x8*)(ap + kt * 1024 + 8);
        const bf16x8 b0 = *(const bf16x8*)(bp + kt * 1024);
        const bf16x8 b1 = *(const bf16x8*)(bp + kt * 1024 + 8);
        const bf16x8 a2 = *(const bf16x8*)(ap + kt * 1024 + 1024);
        const bf16x8 a3 = *(const bf16x8*)(ap + kt * 1024 + 1032);
        const bf16x8 b2 = *(const bf16x8*)(bp + kt * 1024 + 1024);
        const bf16x8 b3 = *(const bf16x8*)(bp + kt * 1024 + 1032);
        acc0 = __builtin_amdgcn_mfma_f32_32x32x16_bf16(a0, b0, acc0, 0, 0, 0);
        acc1 = __builtin_amdgcn_mfma_f32_32x32x16_bf16(a2, b2, acc1, 0, 0, 0);
        acc0 = __builtin_amdgcn_mfma_f32_32x32x16_bf16(a1, b1, acc0, 0, 0, 0);
        acc1 = __builtin_amdgcn_mfma_f32_32x32x16_bf16(a3, b3, acc1, 0, 0, 0);
    }
    const float bo = bias[nt * 32 + l5];
#pragma unroll
    for (int r = 0; r < 16; ++r) {
        const int crow = (r & 3) + 8 * (r >> 2) + 4 * hi;
        out[(size_t)(mt * 32 + crow) * 256 + nt * 32 + l5] =
            acc0[r] + acc1[r] + bo;
    }
}

extern "C" void kernel_launch(void* const* d_in, const int* in_sizes, int n_in,
                              void* d_out, int out_size, void* d_ws, size_t ws_size,
                              hipStream_t stream) {
    const float* x = (const float*)d_in[0];
    const float* mask = (const float*)d_in[1];
    const float* W_qkv = (const float*)d_in[2];
    const float* b_qkv = (const float*)d_in[3];
    const float* W_out = (const float*)d_in[4];
    const float* b_out = (const float*)d_in[5];
    float* out = (float*)d_out;

    const size_t per = (size_t)B_ * H_ * N_ * D_;  // 2,097,152
    short* qb = (short*)d_ws;
    short* kbF = qb + per;
    short* vbF = kbF + per;
    short* maskF = vbF + per;            // N*N = 4,194,304 shorts (8MB)
    short* xF = maskF + (size_t)N_ * N_; // 2,097,152 shorts
    short* wqF = xF + per;               // 196,608 shorts
    short* woF = wqF + 196608;           // 65,536 shorts
    short* aoF = xF;                     // reuse xF (consumed by qkv_mfma)

    prep_relayout<<<2816, 256, 0, stream>>>(x, W_qkv, W_out, mask,
                                            xF, wqF, woF, maskF);
    qkv_mfma<<<1536, 256, 0, stream>>>(xF, wqF, b_qkv, qb, kbF, vbF);
    attn_mfma<<<1024, 256, 0, stream>>>(qb, kbF, vbF, maskF, aoF);
    out_mfma<<<512, 256, 0, stream>>>(aoF, woF, b_out, out);
}

// Round 12
// 83.445 us; speedup vs baseline: 1.0686x; 1.0686x over previous
//
#include <hip/hip_runtime.h>
#include <hip/hip_bf16.h>

#define B_ 4
#define N_ 2048
#define C_ 256
#define H_ 8
#define D_ 32

typedef __attribute__((ext_vector_type(4))) short bf16x4;
typedef __attribute__((ext_vector_type(8))) short bf16x8;
typedef __attribute__((ext_vector_type(16))) float f32x16;

static __device__ __forceinline__ float b2f(short u) {
    unsigned v = ((unsigned)(unsigned short)u) << 16;
    return __builtin_bit_cast(float, v);
}
static __device__ __forceinline__ short f2bs(float f) {
    __hip_bfloat16 h = __float2bfloat16(f);
    return __builtin_bit_cast(short, h);
}

// Fragment k-map (32x32x16 bf16): slot s (0..15), lane-half hi:
//   dd = hi*4 + (s&3) + 8*(s>>2); inverse hi=(dd>>2)&1, s=(dd&3)+4*(dd>>3)
// REGISTER BUDGET (hard-won): attn body = ~128 unified regs/thread = the
// 4-waves/EU budget; every add spilled (R5-R10 history in git log).
// LOAD ORDER (R12 finding): the 44.9us body issues K FIRST, consumes it in
// the S-MFMAs, THEN issues mask (under exp) and V (under pack). Hoisting
// mask/V above the K loads forces the pre-S-MFMA waitcnt to drain ALL
// outstanding loads (vmcnt counts youngest) -> +28% attn time (R9-R11).
// Do not reorder the loads in attn_mfma.

// ---------------------------------------------------------------------------
// Merged prep: x relayout (blocks 0..2047), W relayout (2048..2303),
// mask relayout -> premultiplied bf16 C-fragment order (2304..2815).
// ---------------------------------------------------------------------------
__global__ __launch_bounds__(256) void prep_relayout(const float* __restrict__ x,
                                                     const float* __restrict__ Wq,
                                                     const float* __restrict__ Wo,
                                                     const float* __restrict__ mask,
                                                     short* __restrict__ xF,
                                                     short* __restrict__ wqF,
                                                     short* __restrict__ woF,
                                                     short* __restrict__ maskF) {
    const int t = threadIdx.x;
    const int b = blockIdx.x;
    if (b < 2048) {
        const int idx = b * 256 + t;
        const int row = idx >> 6, c0 = (idx & 63) * 4;
        const float4 f4 = *(const float4*)(x + (size_t)row * 256 + c0);
        const int mt = row >> 5, l5 = row & 31;
        const int kt = c0 >> 5, dd0 = c0 & 31;
        const int hi = (dd0 >> 2) & 1, s0 = 4 * (dd0 >> 3);
        bf16x4 o;
        o[0] = f2bs(f4.x); o[1] = f2bs(f4.y); o[2] = f2bs(f4.z); o[3] = f2bs(f4.w);
        *(bf16x4*)(xF + (((size_t)mt * 8 + kt) * 32 + l5) * 32 + hi * 16 + s0) = o;
    } else if (b < 2304) {
        int idx = (b - 2048) * 256 + t;
        const float* W; short* dst; int ncols;
        if (idx < 49152) { W = Wq; dst = wqF; ncols = 768; }
        else { idx -= 49152; W = Wo; dst = woF; ncols = 256; }
        const int f4pr = ncols >> 2;
        const int row = idx / f4pr, c0 = (idx % f4pr) * 4;
        const float4 f4 = *(const float4*)(W + (size_t)row * ncols + c0);
        const int kt = row >> 5, dd = row & 31;
        const int hi = (dd >> 2) & 1, s = (dd & 3) + 4 * (dd >> 3);
        const float vals[4] = {f4.x, f4.y, f4.z, f4.w};
#pragma unroll
        for (int j = 0; j < 4; ++j) {
            const int col = c0 + j, nt = col >> 5, l5 = col & 31;
            dst[(((size_t)nt * 8 + kt) * 32 + l5) * 32 + hi * 16 + s] = f2bs(vals[j]);
        }
    } else {
        const int bid = b - 2304;           // 0..511
        const int bx = bid & 15, by = bid >> 4;
        const int n = by * 64 + (t & 63);
        const int mt = bx * 4 + (t >> 6);
        const float cf = 0.17677669529663687f * 1.4426950408889634f;
        float v[32];
        const float4* src = (const float4*)(mask + (size_t)n * N_ + mt * 32);
#pragma unroll
        for (int i = 0; i < 8; ++i) {
            const float4 f4 = src[i];
            v[i * 4 + 0] = f4.x; v[i * 4 + 1] = f4.y;
            v[i * 4 + 2] = f4.z; v[i * 4 + 3] = f4.w;
        }
#pragma unroll
        for (int hi = 0; hi < 2; ++hi) {
            bf16x8 o0, o1;
#pragma unroll
            for (int r = 0; r < 16; ++r) {
                const int crow = (r & 3) + 8 * (r >> 2) + 4 * hi;
                const short s = f2bs(cf * (0.1f + 0.9f * v[crow]));
                if (r < 8) o0[r] = s; else o1[r - 8] = s;
            }
            short* dst = maskF + ((size_t)(mt * 2 + hi) * N_ + n) * 16;
            *(bf16x8*)dst = o0;
            *(bf16x8*)(dst + 8) = o1;
        }
    }
}

// ---------------------------------------------------------------------------
// QKV projection, MFMA (dual accumulator for MFMA ILP).
// ---------------------------------------------------------------------------
__global__ __launch_bounds__(256, 4) void qkv_mfma(const short* __restrict__ xF,
                                                   const short* __restrict__ wqF,
                                                   const float* __restrict__ bias,
                                                   short* __restrict__ qb,
                                                   short* __restrict__ kbF,
                                                   short* __restrict__ vbF) {
    __shared__ short sc[4][32 * 34];
    const int t = threadIdx.x;
    const int w = t >> 6, lane = t & 63, l5 = lane & 31, hi = lane >> 5;
    const int tile = blockIdx.x * 4 + w;
    const int nt = tile % 24, mt = tile / 24;
    f32x16 acc0, acc1;
#pragma unroll
    for (int i = 0; i < 16; ++i) { acc0[i] = 0.f; acc1[i] = 0.f; }
    const short* ap = xF + ((size_t)mt * 8 * 32) * 32 + l5 * 32 + hi * 16;
    const short* bp = wqF + ((size_t)nt * 8 * 32) * 32 + l5 * 32 + hi * 16;
#pragma unroll
    for (int kt = 0; kt < 8; kt += 2) {
        const bf16x8 a0 = *(const bf16x8*)(ap + kt * 1024);
        const bf16x8 a1 = *(const bf16x8*)(ap + kt * 1024 + 8);
        const bf16x8 b0 = *(const bf16x8*)(bp + kt * 1024);
        const bf16x8 b1 = *(const bf16x8*)(bp + kt * 1024 + 8);
        const bf16x8 a2 = *(const bf16x8*)(ap + kt * 1024 + 1024);
        const bf16x8 a3 = *(const bf16x8*)(ap + kt * 1024 + 1032);
        const bf16x8 b2 = *(const bf16x8*)(bp + kt * 1024 + 1024);
        const bf16x8 b3 = *(const bf16x8*)(bp + kt * 1024 + 1032);
        acc0 = __builtin_amdgcn_mfma_f32_32x32x16_bf16(a0, b0, acc0, 0, 0, 0);
        acc1 = __builtin_amdgcn_mfma_f32_32x32x16_bf16(a2, b2, acc1, 0, 0, 0);
        acc0 = __builtin_amdgcn_mfma_f32_32x32x16_bf16(a1, b1, acc0, 0, 0, 0);
        acc1 = __builtin_amdgcn_mfma_f32_32x32x16_bf16(a3, b3, acc1, 0, 0, 0);
    }
    const float bq = bias[nt * 32 + l5];
    short* myc = sc[w];
#pragma unroll
    for (int r = 0; r < 16; ++r)
        myc[((r & 3) + 8 * (r >> 2) + 4 * hi) * 34 + l5] =
            f2bs(acc0[r] + acc1[r] + bq);
    __syncthreads();

    const int h = nt & 7, t3 = nt >> 3;
    const int mtk = mt & 63;
    const size_t bh = (size_t)(mt >> 6) * 8 + h;
    if (t3 == 0) {
        const bf16x8 r0 = *(const bf16x8*)(myc + l5 * 34 + hi * 16);
        const bf16x8 r1 = *(const bf16x8*)(myc + l5 * 34 + hi * 16 + 8);
        short* dst = qb + (bh * N_ + (size_t)mtk * 32 + l5) * D_ + hi * 16;
        *(bf16x8*)dst = r0;
        *(bf16x8*)(dst + 8) = r1;
    } else if (t3 == 1) {
        bf16x8 o0, o1;
#pragma unroll
        for (int s = 0; s < 16; ++s) {
            const int dd = hi * 4 + (s & 3) + 8 * (s >> 2);
            const short vv = myc[l5 * 34 + dd];
            if (s < 8) o0[s] = vv; else o1[s - 8] = vv;
        }
        short* dst = kbF + ((bh * 64 + mtk) * 32 + l5) * 32 + hi * 16;
        *(bf16x8*)dst = o0;
        *(bf16x8*)(dst + 8) = o1;
    } else {
        bf16x8 o0, o1;
#pragma unroll
        for (int s = 0; s < 16; ++s) {
            const int nl = hi * 4 + (s & 3) + 8 * (s >> 2);
            const short vv = myc[nl * 34 + l5];
            if (s < 8) o0[s] = vv; else o1[s - 8] = vv;
        }
        short* dst = vbF + ((bh * 64 + mtk) * 32 + l5) * 32 + hi * 16;
        *(bf16x8*)dst = o0;
        *(bf16x8*)(dst + 8) = o1;
    }
}

// ---------------------------------------------------------------------------
// MFMA flash attention — true 44.9us body (Round-3 load order: K first,
// then S-MFMAs, then mask under exp, then V under pack, then PV).
// Grid 1024 = (bh, qg64). Block = 4 waves (split-m x4 in-block), 64 q-rows.
// ---------------------------------------------------------------------------
__global__ __launch_bounds__(256, 4) void attn_mfma(const short* __restrict__ qb,
                                                    const short* __restrict__ kbF,
                                                    const short* __restrict__ vbF,
                                                    const short* __restrict__ maskF,
                                                    short* __restrict__ aoF) {
    __shared__ float red[4][32][33];
    __shared__ float Ls[4][32];
    const int t = threadIdx.x;
    const int w = t >> 6, lane = t & 63, l5 = lane & 31, hi = lane >> 5;
    const int hi4 = hi * 4;
    const int bh = blockIdx.x >> 5, qg = blockIdx.x & 31;
    const int q0 = qg * 64;
    const int nqA = q0 + l5, nqB = q0 + 32 + l5;

    const short* qrA = qb + ((size_t)bh * N_ + nqA) * D_;
    const short* qrB = qb + ((size_t)bh * N_ + nqB) * D_;
    const bf16x8 qfA0 = __builtin_shufflevector(*(const bf16x4*)(qrA + hi4),
                                                *(const bf16x4*)(qrA + hi4 + 8),
                                                0, 1, 2, 3, 4, 5, 6, 7);
    const bf16x8 qfA1 = __builtin_shufflevector(*(const bf16x4*)(qrA + hi4 + 16),
                                                *(const bf16x4*)(qrA + hi4 + 24),
                                                0, 1, 2, 3, 4, 5, 6, 7);
    const bf16x8 qfB0 = __builtin_shufflevector(*(const bf16x4*)(qrB + hi4),
                                                *(const bf16x4*)(qrB + hi4 + 8),
                                                0, 1, 2, 3, 4, 5, 6, 7);
    const bf16x8 qfB1 = __builtin_shufflevector(*(const bf16x4*)(qrB + hi4 + 16),
                                                *(const bf16x4*)(qrB + hi4 + 24),
                                                0, 1, 2, 3, 4, 5, 6, 7);
    f32x16 accA, accB;
#pragma unroll
    for (int i = 0; i < 16; ++i) { accA[i] = 0.f; accB[i] = 0.f; }
    float lsA0 = 0.f, lsA1 = 0.f, lsB0 = 0.f, lsB1 = 0.f;

    const size_t fragbase = (size_t)bh * 64 * 1024;
#pragma unroll 4
    for (int i = 0; i < 16; ++i) {
        const int mt = w * 16 + i;
        // K first — S-MFMA then waits only on the oldest outstanding loads
        const short* kp = kbF + fragbase + (size_t)mt * 1024 + l5 * 32 + hi * 16;
        const bf16x8 af0 = *(const bf16x8*)kp;
        const bf16x8 af1 = *(const bf16x8*)(kp + 8);
        f32x16 sA, sB;
#pragma unroll
        for (int j = 0; j < 16; ++j) { sA[j] = 0.f; sB[j] = 0.f; }
        sA = __builtin_amdgcn_mfma_f32_32x32x16_bf16(af0, qfA0, sA, 0, 0, 0);
        sB = __builtin_amdgcn_mfma_f32_32x32x16_bf16(af0, qfB0, sB, 0, 0, 0);
        sA = __builtin_amdgcn_mfma_f32_32x32x16_bf16(af1, qfA1, sA, 0, 0, 0);
        sB = __builtin_amdgcn_mfma_f32_32x32x16_bf16(af1, qfB1, sB, 0, 0, 0);

        // mask loads issue here; their latency hides under the exp chain
        const short* mpA = maskF + ((size_t)(mt * 2 + hi) * N_ + nqA) * 16;
        const short* mpB = maskF + ((size_t)(mt * 2 + hi) * N_ + nqB) * 16;
        const bf16x8 mA0 = *(const bf16x8*)mpA;
        const bf16x8 mA1 = *(const bf16x8*)(mpA + 8);
        const bf16x8 mB0 = *(const bf16x8*)mpB;
        const bf16x8 mB1 = *(const bf16x8*)(mpB + 8);

        bf16x8 pfA0, pfA1, pfB0, pfB1;
#pragma unroll
        for (int r = 0; r < 16; ++r) {
            const float fmA = b2f(r < 8 ? mA0[r] : mA1[r - 8]);
            const float fmB = b2f(r < 8 ? mB0[r] : mB1[r - 8]);
            const float pA = __builtin_amdgcn_exp2f(sA[r] * fmA);
            const float pB = __builtin_amdgcn_exp2f(sB[r] * fmB);
            if (r < 8) { lsA0 += pA; lsB0 += pB; }
            else       { lsA1 += pA; lsB1 += pB; }
            const short hA = f2bs(pA), hB = f2bs(pB);
            if (r < 8) { pfA0[r] = hA; pfB0[r] = hB; }
            else       { pfA1[r - 8] = hA; pfB1[r - 8] = hB; }
        }
        // V loads issue here; latency hides under the pack tail
        const short* vp = vbF + fragbase + (size_t)mt * 1024 + l5 * 32 + hi * 16;
        const bf16x8 vf0 = *(const bf16x8*)vp;
        const bf16x8 vf1 = *(const bf16x8*)(vp + 8);
        accA = __builtin_amdgcn_mfma_f32_32x32x16_bf16(vf0, pfA0, accA, 0, 0, 0);
        accB = __builtin_amdgcn_mfma_f32_32x32x16_bf16(vf0, pfB0, accB, 0, 0, 0);
        accA = __builtin_amdgcn_mfma_f32_32x32x16_bf16(vf1, pfA1, accA, 0, 0, 0);
        accB = __builtin_amdgcn_mfma_f32_32x32x16_bf16(vf1, pfB1, accB, 0, 0, 0);
    }
    const float lsA = lsA0 + lsA1, lsB = lsB0 + lsB1;

    // two reduction rounds (one per q-tile), reusing the same LDS buffer
    const int h = bh & 7;
    const int gmtb = (bh >> 3) * 64 + qg * 2;
#pragma unroll
    for (int tq = 0; tq < 2; ++tq) {
        if (tq) __syncthreads();
        const float lsum = tq ? lsB : lsA;
        const f32x16 acc = tq ? accB : accA;
        const float lt = lsum + __shfl_xor(lsum, 32);
        Ls[w][l5] = lt;
#pragma unroll
        for (int r = 0; r < 16; ++r)
            red[w][(r & 3) + 8 * (r >> 2) + hi4][l5] = acc[r];
        __syncthreads();
        const int row = t & 31, hi2 = (t >> 5) & 1, sh = t >> 6;
        const float inv = 1.0f / (Ls[0][row] + Ls[1][row] + Ls[2][row] + Ls[3][row]);
        bf16x4 o;
#pragma unroll
        for (int j = 0; j < 4; ++j) {
            const int dd = hi2 * 4 + j + 8 * sh;
            o[j] = f2bs((red[0][dd][row] + red[1][dd][row] +
                         red[2][dd][row] + red[3][dd][row]) * inv);
        }
        const size_t gmt = gmtb + tq;
        *(bf16x4*)(aoF + ((gmt * 8 + h) * 32 + row) * 32 + hi2 * 16 + sh * 4) = o;
    }
}

// ---------------------------------------------------------------------------
// Output projection, MFMA (dual accumulator).
// ---------------------------------------------------------------------------
__global__ __launch_bounds__(256, 4) void out_mfma(const short* __restrict__ aoF,
                                                   const short* __restrict__ woF,
                                                   const float* __restrict__ bias,
                                                   float* __restrict__ out) {
    const int t = threadIdx.x;
    const int w = t >> 6, lane = t & 63, l5 = lane & 31, hi = lane >> 5;
    const int tile = blockIdx.x * 4 + w;
    const int nt = tile & 7, mt = tile >> 3;
    f32x16 acc0, acc1;
#pragma unroll
    for (int i = 0; i < 16; ++i) { acc0[i] = 0.f; acc1[i] = 0.f; }
    const short* ap = aoF + (size_t)mt * 8192 + l5 * 32 + hi * 16;
    const short* bp = woF + (size_t)nt * 8192 + l5 * 32 + hi * 16;
#pragma unroll
    for (int kt = 0; kt < 8; kt += 2) {
        const bf16x8 a0 = *(const bf16x8*)(ap + kt * 1024);
        const bf16x8 a1 = *(const bf16x8*)(ap + kt * 1024 + 8);
        const bf16x8 b0 = *(const bf16x8*)(bp + kt * 1024);
        const bf16x8 b1 = *(const bf16x8*)(bp + kt * 1024 + 8);
        const bf16x8 a2 = *(const bf16x8*)(ap + kt * 1024 + 1024);
        const bf16x8 a3 = *(const bf16x8*)(ap + kt * 1024 + 1032);
        const bf16x8 b2 = *(const bf16x8*)(bp + kt * 1024 + 1024);
        const bf16x8 b3 = *(const bf16x8*)(bp + kt * 1024 + 1032);
        acc0 = __builtin_amdgcn_mfma_f32_32x32x16_bf16(a0, b0, acc0, 0, 0, 0);
        acc1 = __builtin_amdgcn_mfma_f32_32x32x16_bf16(a2, b2, acc1, 0, 0, 0);
        acc0 = __builtin_amdgcn_mfma_f32_32x32x16_bf16(a1, b1, acc0, 0, 0, 0);
        acc1 = __builtin_amdgcn_mfma_f32_32x32x16_bf16(a3, b3, acc1, 0, 0, 0);
    }
    const float bo = bias[nt * 32 + l5];
#pragma unroll
    for (int r = 0; r < 16; ++r) {
        const int crow = (r & 3) + 8 * (r >> 2) + 4 * hi;
        out[(size_t)(mt * 32 + crow) * 256 + nt * 32 + l5] =
            acc0[r] + acc1[r] + bo;
    }
}

extern "C" void kernel_launch(void* const* d_in, const int* in_sizes, int n_in,
                              void* d_out, int out_size, void* d_ws, size_t ws_size,
                              hipStream_t stream) {
    const float* x = (const float*)d_in[0];
    const float* mask = (const float*)d_in[1];
    const float* W_qkv = (const float*)d_in[2];
    const float* b_qkv = (const float*)d_in[3];
    const float* W_out = (const float*)d_in[4];
    const float* b_out = (const float*)d_in[5];
    float* out = (float*)d_out;

    const size_t per = (size_t)B_ * H_ * N_ * D_;  // 2,097,152
    short* qb = (short*)d_ws;
    short* kbF = qb + per;
    short* vbF = kbF + per;
    short* maskF = vbF + per;            // N*N = 4,194,304 shorts (8MB)
    short* xF = maskF + (size_t)N_ * N_; // 2,097,152 shorts
    short* wqF = xF + per;               // 196,608 shorts
    short* woF = wqF + 196608;           // 65,536 shorts
    short* aoF = xF;                     // reuse xF (consumed by qkv_mfma)

    prep_relayout<<<2816, 256, 0, stream>>>(x, W_qkv, W_out, mask,
                                            xF, wqF, woF, maskF);
    qkv_mfma<<<1536, 256, 0, stream>>>(xF, wqF, b_qkv, qb, kbF, vbF);
    attn_mfma<<<1024, 256, 0, stream>>>(qb, kbF, vbF, maskF, aoF);
    out_mfma<<<512, 256, 0, stream>>>(aoF, woF, b_out, out);
}